// Round 10
// baseline (1071.434 us; speedup 1.0000x reference)
//
#include <hip/hip_runtime.h>
#include <hip/hip_bf16.h>
#include <cstdint>
#include <cstddef>
#include <cmath>

#define NN 8192
#define DD 256

using bf16 = __hip_bfloat16;
typedef unsigned short ushort_t;
typedef unsigned int uint32;
typedef short short8 __attribute__((ext_vector_type(8)));
typedef float f32x4 __attribute__((ext_vector_type(4)));

#define GL2LDS(g, l) __builtin_amdgcn_global_load_lds( \
  (const __attribute__((address_space(1))) void*)(g),  \
  (__attribute__((address_space(3))) void*)(l), 16, 0, 0)

// flag: 1 = inputs/outputs bf16, 0 = fp32
__device__ __forceinline__ float ldin(const void* p, int flag, size_t i) {
  return flag ? __bfloat162float(((const bf16*)p)[i]) : ((const float*)p)[i];
}

// ---------- top-8 helpers ----------
__device__ __forceinline__ void ins8(float v, int jj, float (&lv)[8], int (&li)[8]) {
  if (v <= lv[7]) return;
  int cnt = 0;
#pragma unroll
  for (int s = 0; s < 8; ++s) cnt += (lv[s] >= v) ? 1 : 0;
#pragma unroll
  for (int s = 7; s >= 1; --s) {
    bool sh = (s > cnt);
    lv[s] = sh ? lv[s-1] : lv[s];
    li[s] = sh ? li[s-1] : li[s];
  }
#pragma unroll
  for (int s = 0; s < 8; ++s) if (s == cnt) { lv[s] = v; li[s] = jj; }
}

// lexicographic greater: (v desc, idx asc)
__device__ __forceinline__ bool lexgt(float va, int ia, float vb, int ib) {
  return (va > vb) || (va == vb && ia < ib);
}

// butterfly step with bitonic top-8 merge; both lists sorted desc on entry/exit
__device__ __forceinline__ void bimerge(float (&lv)[8], int (&li)[8], int m) {
  float bv[8]; int bi[8];
#pragma unroll
  for (int e = 0; e < 8; ++e) {
    bv[e] = __shfl_xor(lv[e], m, 64);
    bi[e] = __shfl_xor(li[e], m, 64);
  }
#pragma unroll
  for (int e = 0; e < 8; ++e) {
    bool t = lexgt(lv[e], li[e], bv[7 - e], bi[7 - e]);
    lv[e] = t ? lv[e] : bv[7 - e];
    li[e] = t ? li[e] : bi[7 - e];
  }
#pragma unroll
  for (int d = 4; d >= 1; d >>= 1) {
#pragma unroll
    for (int e = 0; e < 8; ++e) {
      if ((e & d) == 0) {
        int f = e + d;
        bool sw = lexgt(lv[f], li[f], lv[e], li[e]);
        float tv = lv[e]; int ti = li[e];
        lv[e] = sw ? lv[f] : lv[e];  li[e] = sw ? li[f] : li[e];
        lv[f] = sw ? tv : lv[f];     li[f] = sw ? ti : li[f];
      }
    }
  }
}

__device__ __forceinline__ void cswap(float& va, int& ia, float& vb, int& ib) {
  bool sw = lexgt(vb, ib, va, ia);
  float tv = va; int ti = ia;
  va = sw ? vb : va; ia = sw ? ib : ia;
  vb = sw ? tv : vb; ib = sw ? ti : ib;
}

// ---------- 0) dtype detection ----------
__global__ void k_detect(const ushort_t* __restrict__ Hu, int* __restrict__ flag) {
  __shared__ int cnt;
  if (threadIdx.x == 0) cnt = 0;
  __syncthreads();
  int sane = 0;
  for (int u = 0; u < 16; ++u) {
    int idx = 2 * (threadIdx.x * 16 + u);
    ushort_t h = Hu[idx];
    int e = (h >> 7) & 0xFF;
    sane += (e >= 113 && e <= 133) ? 1 : 0;
  }
  atomicAdd(&cnt, sane);
  __syncthreads();
  if (threadIdx.x == 0) *flag = (cnt > 2048) ? 1 : 0;
}

// ---------- 1) transpose H -> HT fp32 [DD][NN] ----------
__global__ void k_transposeH(const void* __restrict__ H, const int* __restrict__ pflag,
                             float* __restrict__ HT) {
  int flag = *pflag;
  __shared__ float tile[64][65];
  int i0 = blockIdx.x * 64;
  int c0 = blockIdx.y * 64;
  int tid = threadIdx.x;
  int r = tid >> 2, cb = (tid & 3) * 16;
#pragma unroll
  for (int u = 0; u < 16; ++u)
    tile[r][cb + u] = ldin(H, flag, (size_t)(i0 + r) * DD + c0 + cb + u);
  __syncthreads();
  int c = tid >> 2, rb = (tid & 3) * 16;
#pragma unroll
  for (int u4 = 0; u4 < 4; ++u4) {
    float4 t;
    t.x = tile[rb + 4*u4 + 0][c];
    t.y = tile[rb + 4*u4 + 1][c];
    t.z = tile[rb + 4*u4 + 2][c];
    t.w = tile[rb + 4*u4 + 3][c];
    *(float4*)&HT[(size_t)(c0 + c) * NN + i0 + rb + 4*u4] = t;
  }
}

// ---------- 2) BN stats: one column per block; bitwise sequential chains ----------
__global__ __launch_bounds__(256) void k_statsT(const float* __restrict__ HT,
                                                float* __restrict__ mu32, float* __restrict__ rs32) {
  __shared__ float buf[8192];
  int c = blockIdx.x;
  int tid = threadIdx.x;
#pragma unroll
  for (int it = 0; it < 8; ++it) {
    int idx = it * 1024 + tid * 4;
    *(float4*)&buf[idx] = *(const float4*)&HT[(size_t)c * NN + idx];
  }
  __syncthreads();
  if (tid == 0) {
    float acc = 0.0f;
    for (int r = 0; r < 8192; r += 32) {
      float4 v[8];
#pragma unroll
      for (int q = 0; q < 8; ++q) v[q] = *(const float4*)&buf[r + q * 4];
#pragma unroll
      for (int q = 0; q < 8; ++q) {
        acc = __fadd_rn(acc, v[q].x);
        acc = __fadd_rn(acc, v[q].y);
        acc = __fadd_rn(acc, v[q].z);
        acc = __fadd_rn(acc, v[q].w);
      }
    }
    float mu = __fdiv_rn(acc, 8192.0f);
    float vacc = 0.0f;
    for (int r = 0; r < 8192; r += 32) {
      float4 v[8];
#pragma unroll
      for (int q = 0; q < 8; ++q) v[q] = *(const float4*)&buf[r + q * 4];
#pragma unroll
      for (int q = 0; q < 8; ++q) {
        float d0 = __fsub_rn(v[q].x, mu); vacc = __fadd_rn(vacc, __fmul_rn(d0, d0));
        float d1 = __fsub_rn(v[q].y, mu); vacc = __fadd_rn(vacc, __fmul_rn(d1, d1));
        float d2 = __fsub_rn(v[q].z, mu); vacc = __fadd_rn(vacc, __fmul_rn(d2, d2));
        float d3 = __fsub_rn(v[q].w, mu); vacc = __fadd_rn(vacc, __fmul_rn(d3, d3));
      }
    }
    float var = __fdiv_rn(vacc, 8192.0f);
    mu32[c] = mu;
    rs32[c] = __fdiv_rn(1.0f, sqrtf(__fadd_rn(var, 1e-5f)));
  }
}

// ---------- 3) fused bn + Hx + row-normalize + bf16 hi/lo split, 8 rows/block ----------
__global__ __launch_bounds__(256) void k_hxn(const void* __restrict__ H,
    const int* __restrict__ pflag, const float* __restrict__ mu32, const float* __restrict__ rs32,
    const void* __restrict__ gamma, const void* __restrict__ beta,
    const void* __restrict__ Wt, const void* __restrict__ bt,
    float* __restrict__ Hn, float* __restrict__ F1,
    ushort_t* __restrict__ F1hi, ushort_t* __restrict__ F1lo) {
  int flag = *pflag;
  __shared__ float sHn[8][256];
  __shared__ float sHx[8][256];
  __shared__ float sp[8][16];
  __shared__ float snrm[8];
  const int r0 = blockIdx.x * 8;
  const int n = threadIdx.x;
  float g  = ldin(gamma, flag, n);
  float b  = ldin(beta, flag, n);
  float mu = mu32[n], rs = rs32[n];
#pragma unroll
  for (int r = 0; r < 8; ++r) {
    float t = __fsub_rn(ldin(H, flag, (size_t)(r0 + r) * DD + n), mu);
    t = __fmul_rn(t, rs);
    t = __fmul_rn(t, g);
    t = __fadd_rn(t, b);
    sHn[r][n] = t;
    Hn[(size_t)(r0 + r) * DD + n] = t;
  }
  __syncthreads();
  float acc[8];
#pragma unroll
  for (int r = 0; r < 8; ++r) acc[r] = 0.0f;
#pragma unroll 8
  for (int k = 0; k < DD; ++k) {
    float w = ldin(Wt, flag, (size_t)k * DD + n);
#pragma unroll
    for (int r = 0; r < 8; ++r) acc[r] = fmaf(sHn[r][k], w, acc[r]);
  }
  float btn = ldin(bt, flag, n);
#pragma unroll
  for (int r = 0; r < 8; ++r) sHx[r][n] = __fadd_rn(acc[r], btn);
  __syncthreads();
  if (n < 128) {
    int r = n >> 4, s = n & 15;
    int base = (s >> 3) * 128 + (s & 7);
    float e0 = sHx[r][base];
    float part = __fmul_rn(e0, e0);
#pragma unroll
    for (int t = 1; t < 16; ++t) {
      float e = sHx[r][base + 8 * t];
      part = __fadd_rn(part, __fmul_rn(e, e));
    }
    sp[r][s] = part;
  }
  __syncthreads();
  if (n < 8) {
    const float* p = sp[n];
    float P1 = __fadd_rn(__fadd_rn(__fadd_rn(p[0], p[1]), __fadd_rn(p[2], p[3])),
                         __fadd_rn(__fadd_rn(p[4], p[5]), __fadd_rn(p[6], p[7])));
    float P2 = __fadd_rn(__fadd_rn(__fadd_rn(p[8], p[9]), __fadd_rn(p[10], p[11])),
                         __fadd_rn(__fadd_rn(p[12], p[13]), __fadd_rn(p[14], p[15])));
    snrm[n] = fmaxf(sqrtf(__fadd_rn(P1, P2)), 1e-12f);
  }
  __syncthreads();
#pragma unroll
  for (int r = 0; r < 8; ++r) {
    float xn = __fdiv_rn(sHx[r][n], snrm[r]);
    size_t idx = (size_t)(r0 + r) * DD + n;
    F1[idx] = xn;
    bf16 hi = __float2bfloat16(xn);
    float lo = __fsub_rn(xn, __bfloat162float(hi));
    F1hi[idx] = *(ushort_t*)&hi;
    bf16 lob = __float2bfloat16(lo);
    F1lo[idx] = *(ushort_t*)&lob;
  }
}

// ---------- 4) symmetric S GEMM (lower-triangle tiles) + fused candidate scan ----------
// Tile (it,jt), jt<=it. Per 128x128 tile: normal per-row top-8 of each wave's 64
// cols -> slot 2*jt+wj of row i; transposed (it!=jt) per-col top-8 of each wave's
// 64 rows -> slot 2*it+wi of row j. 128 slots/row, each written exactly once.
__global__ __launch_bounds__(256) void k_gemm_sym(
    const ushort_t* __restrict__ F1hi, const ushort_t* __restrict__ F1lo,
    float* __restrict__ candv, int* __restrict__ candi) {
  __shared__ __align__(16) ushort_t AH[4096];
  __shared__ __align__(16) ushort_t AL[4096];
  __shared__ __align__(16) ushort_t BH[4096];
  __shared__ __align__(16) ushort_t BL[4096];
  const int bidx = blockIdx.x;
  int it = (int)((sqrt(8.0 * (double)bidx + 1.0) - 1.0) * 0.5);
  while ((it + 1) * (it + 2) / 2 <= bidx) ++it;
  while (it * (it + 1) / 2 > bidx) --it;
  const int jt = bidx - it * (it + 1) / 2;

  const int tid = threadIdx.x;
  const int w = tid >> 6, lane = tid & 63;
  const int quad = lane >> 4, l15 = lane & 15;
  const int wi = w >> 1, wj = w & 1;
  const int i0 = it * 128;
  const int j0 = jt * 128;

  const int rofs = lane >> 2;
  const int ccl  = (lane & 3) ^ (rofs & 3);
  const int laneElem = rofs * DD + ccl * 8;

  f32x4 acc[4][4];
#pragma unroll
  for (int fr = 0; fr < 4; ++fr)
#pragma unroll
    for (int fc = 0; fc < 4; ++fc) acc[fr][fc] = (f32x4)0.0f;

  for (int chunk = 0; chunk < 8; ++chunk) {
    const int kofs = chunk * 32;
    __syncthreads();
#pragma unroll
    for (int q = 0; q < 2; ++q) {
      const int s = w * 2 + q;
      const size_t ga = (size_t)(i0 + s * 16) * DD + kofs;
      const size_t gb = (size_t)(j0 + s * 16) * DD + kofs;
      GL2LDS(F1hi + ga + laneElem, &AH[s * 512]);
      GL2LDS(F1lo + ga + laneElem, &AL[s * 512]);
      GL2LDS(F1hi + gb + laneElem, &BH[s * 512]);
      GL2LDS(F1lo + gb + laneElem, &BL[s * 512]);
    }
    __syncthreads();
    short8 ah[4], al[4], bh[4], bl[4];
#pragma unroll
    for (int fr = 0; fr < 4; ++fr) {
      int row = wi * 64 + fr * 16 + l15;
      int g = quad ^ (row & 3);
      ah[fr] = *(const short8*)&AH[row * 32 + g * 8];
      al[fr] = *(const short8*)&AL[row * 32 + g * 8];
    }
#pragma unroll
    for (int fc = 0; fc < 4; ++fc) {
      int row = wj * 64 + fc * 16 + l15;
      int g = quad ^ (row & 3);
      bh[fc] = *(const short8*)&BH[row * 32 + g * 8];
      bl[fc] = *(const short8*)&BL[row * 32 + g * 8];
    }
#pragma unroll
    for (int fr = 0; fr < 4; ++fr)
#pragma unroll
      for (int fc = 0; fc < 4; ++fc) {
        acc[fr][fc] = __builtin_amdgcn_mfma_f32_16x16x32_bf16(ah[fr], bh[fc], acc[fr][fc], 0, 0, 0);
        acc[fr][fc] = __builtin_amdgcn_mfma_f32_16x16x32_bf16(ah[fr], bl[fc], acc[fr][fc], 0, 0, 0);
        acc[fr][fc] = __builtin_amdgcn_mfma_f32_16x16x32_bf16(al[fr], bh[fc], acc[fr][fc], 0, 0, 0);
      }
  }

  // ---- normal scan: per-row top-8 over this wave's 64 cols ----
#pragma unroll
  for (int fr = 0; fr < 4; ++fr) {
#pragma unroll
    for (int reg = 0; reg < 4; ++reg) {
      float sv[4]; int sj[4];
#pragma unroll
      for (int fc = 0; fc < 4; ++fc) {
        sv[fc] = acc[fr][fc][reg];
        sj[fc] = j0 + wj * 64 + fc * 16 + l15;
      }
      cswap(sv[0], sj[0], sv[1], sj[1]);
      cswap(sv[2], sj[2], sv[3], sj[3]);
      cswap(sv[0], sj[0], sv[2], sj[2]);
      cswap(sv[1], sj[1], sv[3], sj[3]);
      cswap(sv[1], sj[1], sv[2], sj[2]);
      float lv[8]; int li[8];
#pragma unroll
      for (int e = 0; e < 4; ++e) { lv[e] = sv[e]; li[e] = sj[e]; }
#pragma unroll
      for (int e = 4; e < 8; ++e) { lv[e] = -3.0e38f; li[e] = 0x7fffffff; }
      bimerge(lv, li, 1);
      bimerge(lv, li, 2);
      bimerge(lv, li, 4);
      bimerge(lv, li, 8);
      int rowg = i0 + wi * 64 + fr * 16 + quad * 4 + reg;
      if (l15 < 8) {
        size_t base = ((size_t)rowg * 128 + 2 * jt + wj) * 8;
        candv[base + l15] = lv[l15];
        candi[base + l15] = li[l15];
      }
    }
  }
  // ---- transposed scan (skip diagonal): per-col top-8 over this wave's 64 rows ----
  if (it != jt) {
#pragma unroll
    for (int fc = 0; fc < 4; ++fc) {
      float lv[8]; int li[8];
#pragma unroll
      for (int e = 0; e < 8; ++e) { lv[e] = -3.0e38f; li[e] = 0x7fffffff; }
#pragma unroll
      for (int fr = 0; fr < 4; ++fr)
#pragma unroll
        for (int reg = 0; reg < 4; ++reg)
          ins8(acc[fr][fc][reg], i0 + wi * 64 + fr * 16 + quad * 4 + reg, lv, li);
      bimerge(lv, li, 16);
      bimerge(lv, li, 32);
      int jg = j0 + wj * 64 + fc * 16 + l15;
      size_t base = ((size_t)jg * 128 + 2 * it + wi) * 8;
#pragma unroll
      for (int e = 0; e < 2; ++e) {
        candv[base + quad * 2 + e] = lv[quad * 2 + e];
        candi[base + quad * 2 + e] = li[quad * 2 + e];
      }
    }
  }
}

// ---------- 5) merge 128 slot-lists -> global top-8 per row (wave per row) ----------
__global__ __launch_bounds__(256) void k_merge(const float* __restrict__ candv,
                                               const int* __restrict__ candi,
                                               int* __restrict__ cand8) {
  int w = threadIdx.x >> 6, lane = threadIdx.x & 63;
  int row = blockIdx.x * 4 + w;
  float lv[8]; int li[8];
#pragma unroll
  for (int e = 0; e < 8; ++e) { lv[e] = -3.0e38f; li[e] = 0x7fffffff; }
  const float* pv = candv + (size_t)row * 1024;
  const int*   pi = candi + (size_t)row * 1024;
#pragma unroll
  for (int s = 0; s < 16; ++s) {
    int t = s * 64 + lane;
    float v = pv[t];
    if (v > lv[7]) ins8(v, pi[t], lv, li);
  }
  bimerge(lv, li, 1);
  bimerge(lv, li, 2);
  bimerge(lv, li, 4);
  bimerge(lv, li, 8);
  bimerge(lv, li, 16);
  bimerge(lv, li, 32);
  if (lane < 8) cand8[row * 8 + lane] = li[lane];
}

// ---------- 6) re-rank candidates with bitwise fp32-numpy mimic chain ----------
__global__ void k_rerank(const float* __restrict__ F1, const int* __restrict__ cand8,
                         int* __restrict__ top5i, float* __restrict__ top5v,
                         float* __restrict__ dinv) {
  int w = threadIdx.x >> 6, lane = threadIdx.x & 63;
  int row = blockIdx.x * 4 + w;
  int jl = 0x7fffffff;
  float a32 = -1.0f;
  if (lane < 8) {
    jl = cand8[row * 8 + lane];
    const float* xi = F1 + (size_t)row * DD;
    const float* xj = F1 + (size_t)jl * DD;
    float acc = 0.0f;
#pragma unroll 8
    for (int k = 0; k < DD; ++k)
      acc = fmaf(xi[k], xj[k], acc);
    float d = fminf(fmaxf(acc, -1.0f), 1.0f);
    float sam = acosf(d);
    float xx = expf(__fmul_rn(-0.2f, sam));
    float sig = __fdiv_rn(1.0f, __fadd_rn(1.0f, expf(-xx)));
    a32 = fmaxf(sig, 0.1f);
  }
  float av[8]; int aj[8];
#pragma unroll
  for (int l = 0; l < 8; ++l) { av[l] = __shfl(a32, l, 64); aj[l] = __shfl(jl, l, 64); }
  if (lane == 0) {
    bool used[8] = {false,false,false,false,false,false,false,false};
    double dsum = 0.0;
#pragma unroll
    for (int k = 0; k < 5; ++k) {
      float bv = -2.0f; int bj = 0x7fffffff; int bs = -1;
#pragma unroll
      for (int s = 0; s < 8; ++s) {
        bool better = (!used[s]) && ((av[s] > bv) || (av[s] == bv && aj[s] < bj));
        bs = better ? s : bs;
        bv = better ? av[s] : bv;
        bj = better ? aj[s] : bj;
      }
#pragma unroll
      for (int s = 0; s < 8; ++s) used[s] = used[s] || (s == bs);
      top5i[row * 5 + k] = bj;
      top5v[row * 5 + k] = bv;
      dsum += (double)bv;
    }
    dinv[row] = (float)(1.0 / sqrt(dsum));
  }
}

// ---------- 7) fused Z = A_hat@Hn and out = LeakyReLU(Z@W_out + srow*b_out) ----------
__global__ __launch_bounds__(256) void k_zout(const float* __restrict__ Hn,
    const int* __restrict__ top5i, const float* __restrict__ top5v,
    const float* __restrict__ dinv, const void* __restrict__ Wo,
    const void* __restrict__ bo, const int* __restrict__ pflag, void* __restrict__ outp) {
  int flag = *pflag;
  __shared__ float sZ[8][256];
  __shared__ float ssr[8];
  const int r0 = blockIdx.x * 8;
  const int n = threadIdx.x;
#pragma unroll
  for (int r = 0; r < 8; ++r) {
    int i = r0 + r;
    float di = dinv[i];
    double z = 0.0;
    float sr = 0.0f;
#pragma unroll
    for (int k = 0; k < 5; ++k) {
      int j = top5i[i * 5 + k];
      float wgt = di * top5v[i * 5 + k] * dinv[j];
      z += (double)wgt * (double)Hn[(size_t)j * DD + n];
      sr += wgt;
    }
    sZ[r][n] = (float)z;
    if (n == 0) ssr[r] = sr;
  }
  __syncthreads();
  float acc[8];
#pragma unroll
  for (int r = 0; r < 8; ++r) acc[r] = 0.0f;
#pragma unroll 8
  for (int k = 0; k < DD; ++k) {
    float w = ldin(Wo, flag, (size_t)k * DD + n);
#pragma unroll
    for (int r = 0; r < 8; ++r) acc[r] = fmaf(sZ[r][k], w, acc[r]);
  }
  float bon = ldin(bo, flag, n);
#pragma unroll
  for (int r = 0; r < 8; ++r) {
    float v = acc[r] + ssr[r] * bon;
    v = (v >= 0.0f) ? v : 0.01f * v;
    size_t idx = (size_t)(r0 + r) * DD + n;
    if (flag) ((bf16*)outp)[idx] = __float2bfloat16(v);
    else      ((float*)outp)[idx] = v;
  }
}

// ---------- 8) fused zero + scatter: block owns 2 rows of A ----------
__global__ __launch_bounds__(256) void k_zeroscatter(void* __restrict__ d_out,
    const int* __restrict__ pflag, const int* __restrict__ top5i,
    const float* __restrict__ top5v) {
  int flag = *pflag;
  size_t esize = flag ? 2 : 4;
  int r0 = blockIdx.x * 2;
  char* Abase = (char*)d_out + (size_t)NN * DD * esize;
  uint4* rowp = (uint4*)(Abase + (size_t)r0 * NN * esize);
  int nvec = (int)((2 * (size_t)NN * esize) >> 4);
  uint4 z; z.x = 0; z.y = 0; z.z = 0; z.w = 0;
  for (int i = threadIdx.x; i < nvec; i += 256) rowp[i] = z;
  __syncthreads();
  int t = threadIdx.x;
  if (t < 10) {
    int r = r0 + t / 5, k = t % 5;
    int col = top5i[r * 5 + k];
    float v = top5v[r * 5 + k];
    if (flag) ((bf16*)Abase)[(size_t)r * NN + col] = __float2bfloat16(v);
    else      ((float*)Abase)[(size_t)r * NN + col] = v;
  }
}

extern "C" void kernel_launch(void* const* d_in, const int* in_sizes, int n_in,
                              void* d_out, int out_size, void* d_ws, size_t ws_size,
                              hipStream_t stream) {
  (void)in_sizes; (void)n_in; (void)out_size; (void)ws_size;
  const void* H     = d_in[0];
  const void* gamma = d_in[1];
  const void* beta  = d_in[2];
  const void* Wt    = d_in[3];
  const void* bt    = d_in[4];
  const void* Wo    = d_in[5];
  const void* bo    = d_in[6];

  // scratch zone inside the A-output region (valid in both dtype worlds), freed by k_zeroscatter
  const size_t MB = 1048576;
  char* zb = (char*)d_out + 8 * MB;
  float*    Hn32  = (float*)(zb + 0);              // 8 MiB
  float*    F1_32 = (float*)(zb + 8 * MB);         // 8 MiB
  ushort_t* F1hi  = (ushort_t*)(zb + 16 * MB);     // 4 MiB
  ushort_t* F1lo  = (ushort_t*)(zb + 20 * MB);     // 4 MiB
  float*    HT    = (float*)(zb + 24 * MB);        // 8 MiB [DD][NN]
  float*    mu32  = (float*)(zb + 32 * MB);        // 1 KiB
  float*    rs32  = (float*)(zb + 32 * MB + 4096); // 1 KiB
  int*      cand8 = (int*)(zb + 32 * MB + 8192);   // 256 KiB
  float*    dinv  = (float*)(zb + 33 * MB);        // 32 KiB
  float*    candv = (float*)(zb + 34 * MB);        // 32 MiB [row][128][8]
  int*      candi = (int*)(zb + 66 * MB);          // 32 MiB
  // zone ends at +98 MiB < 124 MiB (bf16-world A bound)

  // d_ws: only what must survive into k_zeroscatter
  char* ws = (char*)d_ws;
  int*   flag  = (int*)(ws + 0);
  int*   top5i = (int*)(ws + 256);       // 160 KiB
  float* top5v = (float*)(ws + 164096);  // 160 KiB

  k_detect<<<dim3(1), dim3(256), 0, stream>>>((const ushort_t*)H, flag);
  k_transposeH<<<dim3(128, 4), dim3(256), 0, stream>>>(H, flag, HT);
  k_statsT<<<dim3(256), dim3(256), 0, stream>>>(HT, mu32, rs32);
  k_hxn<<<dim3(1024), dim3(256), 0, stream>>>(H, flag, mu32, rs32, gamma, beta,
                                              Wt, bt, Hn32, F1_32, F1hi, F1lo);
  k_gemm_sym<<<dim3(2080), dim3(256), 0, stream>>>(F1hi, F1lo, candv, candi);
  k_merge<<<dim3(2048), dim3(256), 0, stream>>>(candv, candi, cand8);
  k_rerank<<<dim3(2048), dim3(256), 0, stream>>>(F1_32, cand8, top5i, top5v, dinv);
  k_zout<<<dim3(1024), dim3(256), 0, stream>>>(Hn32, top5i, top5v, dinv, Wo, bo, flag, d_out);
  k_zeroscatter<<<dim3(4096), dim3(256), 0, stream>>>(d_out, flag, top5i, top5v);
}

// Round 11
// 814.769 us; speedup vs baseline: 1.3150x; 1.3150x over previous
//
#include <hip/hip_runtime.h>
#include <hip/hip_bf16.h>
#include <cstdint>
#include <cstddef>

#define NN 8192
#define DD 256

using bf16 = __hip_bfloat16;
typedef unsigned short ushort_t;
typedef unsigned int uint32;
typedef short short8 __attribute__((ext_vector_type(8)));
typedef float f32x4 __attribute__((ext_vector_type(4)));

#define GL2LDS(g, l) __builtin_amdgcn_global_load_lds( \
  (const __attribute__((address_space(1))) void*)(g),  \
  (__attribute__((address_space(3))) void*)(l), 16, 0, 0)

// flag: 1 = inputs/outputs bf16, 0 = fp32
__device__ __forceinline__ float ldin(const void* p, int flag, size_t i) {
  return flag ? __bfloat162float(((const bf16*)p)[i]) : ((const float*)p)[i];
}

// ---------- top-8 helpers ----------
__device__ __forceinline__ void ins8(float v, int jj, float (&lv)[8], int (&li)[8]) {
  if (v <= lv[7]) return;
  int cnt = 0;
#pragma unroll
  for (int s = 0; s < 8; ++s) cnt += (lv[s] >= v) ? 1 : 0;
#pragma unroll
  for (int s = 7; s >= 1; --s) {
    bool sh = (s > cnt);
    lv[s] = sh ? lv[s-1] : lv[s];
    li[s] = sh ? li[s-1] : li[s];
  }
#pragma unroll
  for (int s = 0; s < 8; ++s) if (s == cnt) { lv[s] = v; li[s] = jj; }
}

// lexicographic greater: (v desc, idx asc)
__device__ __forceinline__ bool lexgt(float va, int ia, float vb, int ib) {
  return (va > vb) || (va == vb && ia < ib);
}

// butterfly step with bitonic top-8 merge; both lists sorted desc on entry/exit
__device__ __forceinline__ void bimerge(float (&lv)[8], int (&li)[8], int m) {
  float bv[8]; int bi[8];
#pragma unroll
  for (int e = 0; e < 8; ++e) {
    bv[e] = __shfl_xor(lv[e], m, 64);
    bi[e] = __shfl_xor(li[e], m, 64);
  }
#pragma unroll
  for (int e = 0; e < 8; ++e) {
    bool t = lexgt(lv[e], li[e], bv[7 - e], bi[7 - e]);
    lv[e] = t ? lv[e] : bv[7 - e];
    li[e] = t ? li[e] : bi[7 - e];
  }
#pragma unroll
  for (int d = 4; d >= 1; d >>= 1) {
#pragma unroll
    for (int e = 0; e < 8; ++e) {
      if ((e & d) == 0) {
        int f = e + d;
        bool sw = lexgt(lv[f], li[f], lv[e], li[e]);
        float tv = lv[e]; int ti = li[e];
        lv[e] = sw ? lv[f] : lv[e];  li[e] = sw ? li[f] : li[e];
        lv[f] = sw ? tv : lv[f];     li[f] = sw ? ti : li[f];
      }
    }
  }
}

// ---------- 0) dtype detection ----------
__global__ void k_detect(const ushort_t* __restrict__ Hu, int* __restrict__ flag) {
  __shared__ int cnt;
  if (threadIdx.x == 0) cnt = 0;
  __syncthreads();
  int sane = 0;
  for (int u = 0; u < 16; ++u) {
    int idx = 2 * (threadIdx.x * 16 + u);
    ushort_t h = Hu[idx];
    int e = (h >> 7) & 0xFF;
    sane += (e >= 113 && e <= 133) ? 1 : 0;
  }
  atomicAdd(&cnt, sane);
  __syncthreads();
  if (threadIdx.x == 0) *flag = (cnt > 2048) ? 1 : 0;
}

// ---------- 1) transpose H -> HT fp32 [DD][NN] ----------
__global__ void k_transposeH(const void* __restrict__ H, const int* __restrict__ pflag,
                             float* __restrict__ HT) {
  int flag = *pflag;
  __shared__ float tile[64][65];
  int i0 = blockIdx.x * 64;
  int c0 = blockIdx.y * 64;
  int tid = threadIdx.x;
  int r = tid >> 2, cb = (tid & 3) * 16;
#pragma unroll
  for (int u = 0; u < 16; ++u)
    tile[r][cb + u] = ldin(H, flag, (size_t)(i0 + r) * DD + c0 + cb + u);
  __syncthreads();
  int c = tid >> 2, rb = (tid & 3) * 16;
#pragma unroll
  for (int u4 = 0; u4 < 4; ++u4) {
    float4 t;
    t.x = tile[rb + 4*u4 + 0][c];
    t.y = tile[rb + 4*u4 + 1][c];
    t.z = tile[rb + 4*u4 + 2][c];
    t.w = tile[rb + 4*u4 + 3][c];
    *(float4*)&HT[(size_t)(c0 + c) * NN + i0 + rb + 4*u4] = t;
  }
}

// ---------- 2) BN stats: one column per block; bitwise sequential chains ----------
__global__ __launch_bounds__(256) void k_statsT(const float* __restrict__ HT,
                                                float* __restrict__ mu32, float* __restrict__ rs32) {
  __shared__ float buf[8192];
  int c = blockIdx.x;
  int tid = threadIdx.x;
#pragma unroll
  for (int it = 0; it < 8; ++it) {
    int idx = it * 1024 + tid * 4;
    *(float4*)&buf[idx] = *(const float4*)&HT[(size_t)c * NN + idx];
  }
  __syncthreads();
  if (tid == 0) {
    float acc = 0.0f;
    for (int r = 0; r < 8192; r += 32) {
      float4 v[8];
#pragma unroll
      for (int q = 0; q < 8; ++q) v[q] = *(const float4*)&buf[r + q * 4];
#pragma unroll
      for (int q = 0; q < 8; ++q) {
        acc = __fadd_rn(acc, v[q].x);
        acc = __fadd_rn(acc, v[q].y);
        acc = __fadd_rn(acc, v[q].z);
        acc = __fadd_rn(acc, v[q].w);
      }
    }
    float mu = __fdiv_rn(acc, 8192.0f);
    float vacc = 0.0f;
    for (int r = 0; r < 8192; r += 32) {
      float4 v[8];
#pragma unroll
      for (int q = 0; q < 8; ++q) v[q] = *(const float4*)&buf[r + q * 4];
#pragma unroll
      for (int q = 0; q < 8; ++q) {
        float d0 = __fsub_rn(v[q].x, mu); vacc = __fadd_rn(vacc, __fmul_rn(d0, d0));
        float d1 = __fsub_rn(v[q].y, mu); vacc = __fadd_rn(vacc, __fmul_rn(d1, d1));
        float d2 = __fsub_rn(v[q].z, mu); vacc = __fadd_rn(vacc, __fmul_rn(d2, d2));
        float d3 = __fsub_rn(v[q].w, mu); vacc = __fadd_rn(vacc, __fmul_rn(d3, d3));
      }
    }
    float var = __fdiv_rn(vacc, 8192.0f);
    mu32[c] = mu;
    rs32[c] = __fdiv_rn(1.0f, sqrtf(__fadd_rn(var, 1e-5f)));
  }
}

// ---------- 3) fused bn + Hx + row-normalize + bf16 hi/lo split, 8 rows/block ----------
__global__ __launch_bounds__(256) void k_hxn(const void* __restrict__ H,
    const int* __restrict__ pflag, const float* __restrict__ mu32, const float* __restrict__ rs32,
    const void* __restrict__ gamma, const void* __restrict__ beta,
    const void* __restrict__ Wt, const void* __restrict__ bt,
    float* __restrict__ Hn, float* __restrict__ F1,
    ushort_t* __restrict__ F1hi, ushort_t* __restrict__ F1lo) {
  int flag = *pflag;
  __shared__ float sHn[8][256];
  __shared__ float sHx[8][256];
  __shared__ float sp[8][16];
  __shared__ float snrm[8];
  const int r0 = blockIdx.x * 8;
  const int n = threadIdx.x;
  float g  = ldin(gamma, flag, n);
  float b  = ldin(beta, flag, n);
  float mu = mu32[n], rs = rs32[n];
#pragma unroll
  for (int r = 0; r < 8; ++r) {
    float t = __fsub_rn(ldin(H, flag, (size_t)(r0 + r) * DD + n), mu);
    t = __fmul_rn(t, rs);
    t = __fmul_rn(t, g);
    t = __fadd_rn(t, b);
    sHn[r][n] = t;
    Hn[(size_t)(r0 + r) * DD + n] = t;
  }
  __syncthreads();
  float acc[8];
#pragma unroll
  for (int r = 0; r < 8; ++r) acc[r] = 0.0f;
#pragma unroll 8
  for (int k = 0; k < DD; ++k) {
    float w = ldin(Wt, flag, (size_t)k * DD + n);
#pragma unroll
    for (int r = 0; r < 8; ++r) acc[r] = fmaf(sHn[r][k], w, acc[r]);
  }
  float btn = ldin(bt, flag, n);
#pragma unroll
  for (int r = 0; r < 8; ++r) sHx[r][n] = __fadd_rn(acc[r], btn);
  __syncthreads();
  if (n < 128) {
    int r = n >> 4, s = n & 15;
    int base = (s >> 3) * 128 + (s & 7);
    float e0 = sHx[r][base];
    float part = __fmul_rn(e0, e0);
#pragma unroll
    for (int t = 1; t < 16; ++t) {
      float e = sHx[r][base + 8 * t];
      part = __fadd_rn(part, __fmul_rn(e, e));
    }
    sp[r][s] = part;
  }
  __syncthreads();
  if (n < 8) {
    const float* p = sp[n];
    float P1 = __fadd_rn(__fadd_rn(__fadd_rn(p[0], p[1]), __fadd_rn(p[2], p[3])),
                         __fadd_rn(__fadd_rn(p[4], p[5]), __fadd_rn(p[6], p[7])));
    float P2 = __fadd_rn(__fadd_rn(__fadd_rn(p[8], p[9]), __fadd_rn(p[10], p[11])),
                         __fadd_rn(__fadd_rn(p[12], p[13]), __fadd_rn(p[14], p[15])));
    snrm[n] = fmaxf(sqrtf(__fadd_rn(P1, P2)), 1e-12f);
  }
  __syncthreads();
#pragma unroll
  for (int r = 0; r < 8; ++r) {
    float xn = __fdiv_rn(sHx[r][n], snrm[r]);
    size_t idx = (size_t)(r0 + r) * DD + n;
    F1[idx] = xn;
    bf16 hi = __float2bfloat16(xn);
    float lo = __fsub_rn(xn, __bfloat162float(hi));
    F1hi[idx] = *(ushort_t*)&hi;
    bf16 lob = __float2bfloat16(lo);
    F1lo[idx] = *(ushort_t*)&lob;
  }
}

// ---------- 4) S-chunk GEMM via global_load_lds: S = hh + hl + lh ----------
__global__ __launch_bounds__(256) void k_gemm_s(
    const ushort_t* __restrict__ F1hi, const ushort_t* __restrict__ F1lo,
    int jc, float* __restrict__ S) {
  __shared__ __align__(16) ushort_t AH[4096];
  __shared__ __align__(16) ushort_t AL[4096];
  __shared__ __align__(16) ushort_t BH[4096];
  __shared__ __align__(16) ushort_t BL[4096];
  const int tid = threadIdx.x;
  const int w = tid >> 6, lane = tid & 63;
  const int quad = lane >> 4, l15 = lane & 15;
  const int wi = w >> 1, wj = w & 1;
  const int i0 = blockIdx.y * 128;
  const int j0loc = blockIdx.x * 128;
  const int j0 = jc * 2048 + j0loc;

  const int rofs = lane >> 2;
  const int ccl  = (lane & 3) ^ (rofs & 3);
  const int laneElem = rofs * DD + ccl * 8;

  f32x4 acc[4][4];
#pragma unroll
  for (int fr = 0; fr < 4; ++fr)
#pragma unroll
    for (int fc = 0; fc < 4; ++fc) acc[fr][fc] = (f32x4)0.0f;

  for (int chunk = 0; chunk < 8; ++chunk) {
    const int kofs = chunk * 32;
    __syncthreads();
#pragma unroll
    for (int q = 0; q < 2; ++q) {
      const int s = w * 2 + q;
      const size_t ga = (size_t)(i0 + s * 16) * DD + kofs;
      const size_t gb = (size_t)(j0 + s * 16) * DD + kofs;
      GL2LDS(F1hi + ga + laneElem, &AH[s * 512]);
      GL2LDS(F1lo + ga + laneElem, &AL[s * 512]);
      GL2LDS(F1hi + gb + laneElem, &BH[s * 512]);
      GL2LDS(F1lo + gb + laneElem, &BL[s * 512]);
    }
    __syncthreads();
    short8 ah[4], al[4], bh[4], bl[4];
#pragma unroll
    for (int fr = 0; fr < 4; ++fr) {
      int row = wi * 64 + fr * 16 + l15;
      int g = quad ^ (row & 3);
      ah[fr] = *(const short8*)&AH[row * 32 + g * 8];
      al[fr] = *(const short8*)&AL[row * 32 + g * 8];
    }
#pragma unroll
    for (int fc = 0; fc < 4; ++fc) {
      int row = wj * 64 + fc * 16 + l15;
      int g = quad ^ (row & 3);
      bh[fc] = *(const short8*)&BH[row * 32 + g * 8];
      bl[fc] = *(const short8*)&BL[row * 32 + g * 8];
    }
#pragma unroll
    for (int fr = 0; fr < 4; ++fr)
#pragma unroll
      for (int fc = 0; fc < 4; ++fc) {
        acc[fr][fc] = __builtin_amdgcn_mfma_f32_16x16x32_bf16(ah[fr], bh[fc], acc[fr][fc], 0, 0, 0);
        acc[fr][fc] = __builtin_amdgcn_mfma_f32_16x16x32_bf16(ah[fr], bl[fc], acc[fr][fc], 0, 0, 0);
        acc[fr][fc] = __builtin_amdgcn_mfma_f32_16x16x32_bf16(al[fr], bh[fc], acc[fr][fc], 0, 0, 0);
      }
  }
#pragma unroll
  for (int fr = 0; fr < 4; ++fr) {
#pragma unroll
    for (int reg = 0; reg < 4; ++reg) {
      int row = i0 + wi * 64 + fr * 16 + quad * 4 + reg;
#pragma unroll
      for (int fc = 0; fc < 4; ++fc) {
        int coll = j0loc + wj * 64 + fc * 16 + l15;
        S[(size_t)row * 2048 + coll] = acc[fr][fc][reg];
      }
    }
  }
}

// ---------- 5) per-chunk top-8 scan of S; guarded ins8 + bitonic merge ----------
__global__ __launch_bounds__(256) void k_scan(const float* __restrict__ S, int jc,
                                              float* __restrict__ candv, int* __restrict__ candi) {
  int w = threadIdx.x >> 6, lane = threadIdx.x & 63;
  int row = blockIdx.x * 4 + w;
  const int jbase = jc * 2048;
  float lv[8]; int li[8];
#pragma unroll
  for (int e = 0; e < 8; ++e) { lv[e] = -3.0e38f; li[e] = 0x7fffffff; }
  const float* p = S + (size_t)row * 2048;
#pragma unroll
  for (int it = 0; it < 8; ++it) {
    int col = it * 256 + lane * 4;
    float4 v = *(const float4*)&p[col];
    float m4 = fmaxf(fmaxf(v.x, v.y), fmaxf(v.z, v.w));
    if (m4 > lv[7]) {
      ins8(v.x, jbase + col + 0, lv, li);
      ins8(v.y, jbase + col + 1, lv, li);
      ins8(v.z, jbase + col + 2, lv, li);
      ins8(v.w, jbase + col + 3, lv, li);
    }
  }
  bimerge(lv, li, 1);
  bimerge(lv, li, 2);
  bimerge(lv, li, 4);
  bimerge(lv, li, 8);
  bimerge(lv, li, 16);
  bimerge(lv, li, 32);
  if (lane == 0) {
    size_t base = ((size_t)row * 4 + jc) * 8;
#pragma unroll
    for (int e = 0; e < 8; ++e) { candv[base + e] = lv[e]; candi[base + e] = li[e]; }
  }
}

// ---------- 6) fused merge (32 entries/row, butterfly) + bitwise fp32 rerank ----------
__global__ void k_rerank(const float* __restrict__ F1, const float* __restrict__ candv,
                         const int* __restrict__ candi,
                         int* __restrict__ top5i, float* __restrict__ top5v,
                         float* __restrict__ dinv) {
  int w = threadIdx.x >> 6, lane = threadIdx.x & 63;
  int row = blockIdx.x * 4 + w;
  // merge phase: lanes 0..31 each hold one candidate entry, butterfly to top-8
  float lv[8]; int li[8];
#pragma unroll
  for (int e = 0; e < 8; ++e) { lv[e] = -3.0e38f; li[e] = 0x7fffffff; }
  if (lane < 32) {
    lv[0] = candv[(size_t)row * 32 + lane];
    li[0] = candi[(size_t)row * 32 + lane];
  }
  bimerge(lv, li, 1);
  bimerge(lv, li, 2);
  bimerge(lv, li, 4);
  bimerge(lv, li, 8);
  bimerge(lv, li, 16);
  // lanes 0..31 now hold the row's top-8 (sorted desc, idx-asc ties)
  int jl = 0x7fffffff;
  float a32 = -1.0f;
  if (lane < 8) {
    jl = li[0];
#pragma unroll
    for (int e = 1; e < 8; ++e) jl = (lane == e) ? li[e] : jl;
    const float* xi = F1 + (size_t)row * DD;
    const float* xj = F1 + (size_t)jl * DD;
    float acc = 0.0f;
#pragma unroll 8
    for (int k = 0; k < DD; ++k)
      acc = fmaf(xi[k], xj[k], acc);
    float d = fminf(fmaxf(acc, -1.0f), 1.0f);
    float sam = acosf(d);
    float xx = expf(__fmul_rn(-0.2f, sam));
    float sig = __fdiv_rn(1.0f, __fadd_rn(1.0f, expf(-xx)));
    a32 = fmaxf(sig, 0.1f);
  }
  float av[8]; int aj[8];
#pragma unroll
  for (int l = 0; l < 8; ++l) { av[l] = __shfl(a32, l, 64); aj[l] = __shfl(jl, l, 64); }
  if (lane == 0) {
    bool used[8] = {false,false,false,false,false,false,false,false};
    double dsum = 0.0;
#pragma unroll
    for (int k = 0; k < 5; ++k) {
      float bv = -2.0f; int bj = 0x7fffffff; int bs = -1;
#pragma unroll
      for (int s = 0; s < 8; ++s) {
        bool better = (!used[s]) && ((av[s] > bv) || (av[s] == bv && aj[s] < bj));
        bs = better ? s : bs;
        bv = better ? av[s] : bv;
        bj = better ? aj[s] : bj;
      }
#pragma unroll
      for (int s = 0; s < 8; ++s) used[s] = used[s] || (s == bs);
      top5i[row * 5 + k] = bj;
      top5v[row * 5 + k] = bv;
      dsum += (double)bv;
    }
    dinv[row] = (float)(1.0 / sqrt(dsum));
  }
}

// ---------- 7) fused Z = A_hat@Hn and out = LeakyReLU(Z@W_out + srow*b_out) ----------
__global__ __launch_bounds__(256) void k_zout(const float* __restrict__ Hn,
    const int* __restrict__ top5i, const float* __restrict__ top5v,
    const float* __restrict__ dinv, const void* __restrict__ Wo,
    const void* __restrict__ bo, const int* __restrict__ pflag, void* __restrict__ outp) {
  int flag = *pflag;
  __shared__ float sZ[8][256];
  __shared__ float ssr[8];
  const int r0 = blockIdx.x * 8;
  const int n = threadIdx.x;
#pragma unroll
  for (int r = 0; r < 8; ++r) {
    int i = r0 + r;
    float di = dinv[i];
    double z = 0.0;
    float sr = 0.0f;
#pragma unroll
    for (int k = 0; k < 5; ++k) {
      int j = top5i[i * 5 + k];
      float wgt = di * top5v[i * 5 + k] * dinv[j];
      z += (double)wgt * (double)Hn[(size_t)j * DD + n];
      sr += wgt;
    }
    sZ[r][n] = (float)z;
    if (n == 0) ssr[r] = sr;
  }
  __syncthreads();
  float acc[8];
#pragma unroll
  for (int r = 0; r < 8; ++r) acc[r] = 0.0f;
#pragma unroll 8
  for (int k = 0; k < DD; ++k) {
    float w = ldin(Wo, flag, (size_t)k * DD + n);
#pragma unroll
    for (int r = 0; r < 8; ++r) acc[r] = fmaf(sZ[r][k], w, acc[r]);
  }
  float bon = ldin(bo, flag, n);
#pragma unroll
  for (int r = 0; r < 8; ++r) {
    float v = acc[r] + ssr[r] * bon;
    v = (v >= 0.0f) ? v : 0.01f * v;
    size_t idx = (size_t)(r0 + r) * DD + n;
    if (flag) ((bf16*)outp)[idx] = __float2bfloat16(v);
    else      ((float*)outp)[idx] = v;
  }
}

// ---------- 8) fused zero + scatter: block owns 2 rows of A ----------
__global__ __launch_bounds__(256) void k_zeroscatter(void* __restrict__ d_out,
    const int* __restrict__ pflag, const int* __restrict__ top5i,
    const float* __restrict__ top5v) {
  int flag = *pflag;
  size_t esize = flag ? 2 : 4;
  int r0 = blockIdx.x * 2;
  char* Abase = (char*)d_out + (size_t)NN * DD * esize;
  uint4* rowp = (uint4*)(Abase + (size_t)r0 * NN * esize);
  int nvec = (int)((2 * (size_t)NN * esize) >> 4);
  uint4 z; z.x = 0; z.y = 0; z.z = 0; z.w = 0;
  for (int i = threadIdx.x; i < nvec; i += 256) rowp[i] = z;
  __syncthreads();
  int t = threadIdx.x;
  if (t < 10) {
    int r = r0 + t / 5, k = t % 5;
    int col = top5i[r * 5 + k];
    float v = top5v[r * 5 + k];
    if (flag) ((bf16*)Abase)[(size_t)r * NN + col] = __float2bfloat16(v);
    else      ((float*)Abase)[(size_t)r * NN + col] = v;
  }
}

extern "C" void kernel_launch(void* const* d_in, const int* in_sizes, int n_in,
                              void* d_out, int out_size, void* d_ws, size_t ws_size,
                              hipStream_t stream) {
  (void)in_sizes; (void)n_in; (void)out_size; (void)ws_size;
  const void* H     = d_in[0];
  const void* gamma = d_in[1];
  const void* beta  = d_in[2];
  const void* Wt    = d_in[3];
  const void* bt    = d_in[4];
  const void* Wo    = d_in[5];
  const void* bo    = d_in[6];

  // scratch zone inside the A-output region (valid in both dtype worlds), freed by k_zeroscatter
  const size_t MB = 1048576;
  char* zb = (char*)d_out + 8 * MB;
  float*    Hn32  = (float*)(zb + 0);              // 8 MiB
  float*    F1_32 = (float*)(zb + 8 * MB);         // 8 MiB
  ushort_t* F1hi  = (ushort_t*)(zb + 16 * MB);     // 4 MiB
  ushort_t* F1lo  = (ushort_t*)(zb + 20 * MB);     // 4 MiB
  float*    candv = (float*)(zb + 24 * MB);        // 1 MiB
  int*      candi = (int*)(zb + 25 * MB);          // 1 MiB
  float*    HT    = (float*)(zb + 36 * MB);        // 8 MiB [DD][NN]
  float*    mu32  = (float*)(zb + 44 * MB);        // 1 KiB
  float*    rs32  = (float*)(zb + 44 * MB + 4096); // 1 KiB
  float*    dinv  = (float*)(zb + 44 * MB + 270336);  // 32 KiB
  float*    Schunk= (float*)(zb + 48 * MB);        // 64 MiB [8192][2048], ends +112 < 124

  // d_ws: only what must survive into k_zeroscatter
  char* ws = (char*)d_ws;
  int*   flag  = (int*)(ws + 0);
  int*   top5i = (int*)(ws + 256);       // 160 KiB
  float* top5v = (float*)(ws + 164096);  // 160 KiB

  k_detect<<<dim3(1), dim3(256), 0, stream>>>((const ushort_t*)H, flag);
  k_transposeH<<<dim3(128, 4), dim3(256), 0, stream>>>(H, flag, HT);
  k_statsT<<<dim3(256), dim3(256), 0, stream>>>(HT, mu32, rs32);
  k_hxn<<<dim3(1024), dim3(256), 0, stream>>>(H, flag, mu32, rs32, gamma, beta,
                                              Wt, bt, Hn32, F1_32, F1hi, F1lo);
  for (int jc = 0; jc < 4; ++jc) {
    k_gemm_s<<<dim3(16, 64), dim3(256), 0, stream>>>(F1hi, F1lo, jc, Schunk);
    k_scan<<<dim3(2048), dim3(256), 0, stream>>>(Schunk, jc, candv, candi);
  }
  k_rerank<<<dim3(2048), dim3(256), 0, stream>>>(F1_32, candv, candi, top5i, top5v, dinv);
  k_zout<<<dim3(1024), dim3(256), 0, stream>>>(Hn32, top5i, top5v, dinv, Wo, bo, flag, d_out);
  k_zeroscatter<<<dim3(4096), dim3(256), 0, stream>>>(d_out, flag, top5i, top5v);
}